// Round 10
// baseline (440.699 us; speedup 1.0000x reference)
//
#include <hip/hip_runtime.h>

// Problem constants (from reference)
constexpr int NSAMP  = 2048;
constexpr int NDIM   = 3072;   // H*W*C = 32*32*3
constexpr int NTRANS = 3072;   // NKERNEL*NCOMP = 192*16
constexpr int NBIN   = 200;
constexpr int NCLASS = 10;
constexpr int NPATCH = 192;
constexpr int BLK    = 256;
constexpr int NL     = 128;    // search-LUT bins over [-4,4]; bracket<=8
constexpr int LUTS   = 136;    // LDS lut row stride in bytes

// ---------------- P0: class bucketing (ballot) -> inverse permutation -----
// inv[slot] = original sample index; cls_off = class segment offsets.
// Also zeroes the logj output (fused kernel accumulates into it atomically).
__global__ __launch_bounds__(1024)
void p0_prep(const int* __restrict__ label,
             int* __restrict__ inv,       // (NSAMP) slot -> sample
             int* __restrict__ cls_off,   // (NCLASS+1)
             float* __restrict__ logj)    // (NSAMP) output, zeroed here
{
    __shared__ int s_lab[NSAMP];
    __shared__ int s_cnt[32][NCLASS];
    __shared__ int s_pre[32][NCLASS];
    __shared__ int s_tot[NCLASS];
    __shared__ int s_off[NCLASS + 1];
    const int tid  = threadIdx.x;
    const int lane = tid & 63;
    const int wv   = tid >> 6;

    for (int i = tid; i < NSAMP; i += 1024) {
        s_lab[i] = label[i];
        logj[i] = 0.f;
    }
    __syncthreads();

    const unsigned long long ltmask = ((unsigned long long)1 << lane) - 1;
    int myrank[2], myc[2];
    #pragma unroll
    for (int pass = 0; pass < 2; ++pass) {
        const int n = pass * 1024 + tid;
        const int c = s_lab[n];
        myc[pass] = c;
        int r = 0;
        #pragma unroll
        for (int cls = 0; cls < NCLASS; ++cls) {
            const unsigned long long b = __ballot(c == cls);
            if (lane == 0) s_cnt[pass * 16 + wv][cls] = __popcll(b);
            if (cls == c)  r = __popcll(b & ltmask);
        }
        myrank[pass] = r;
    }
    __syncthreads();

    if (tid < 32 * NCLASS) {
        const int seg = tid & 31;
        const int cls = tid >> 5;
        int acc = 0;
        for (int s = 0; s < seg; ++s) acc += s_cnt[s][cls];
        s_pre[seg][cls] = acc;
        if (seg == 31) s_tot[cls] = acc + s_cnt[31][cls];
    }
    __syncthreads();
    if (tid == 0) {
        int a = 0;
        for (int c = 0; c < NCLASS; ++c) { s_off[c] = a; a += s_tot[c]; }
        s_off[NCLASS] = a;
    }
    __syncthreads();

    #pragma unroll
    for (int pass = 0; pass < 2; ++pass) {
        const int n    = pass * 1024 + tid;
        const int seg  = pass * 16 + wv;
        const int c    = myc[pass];
        const int slot = s_off[c] + s_pre[seg][c] + myrank[pass];
        inv[slot] = n;
    }
    if (tid <= NCLASS) cls_off[tid] = s_off[tid];
}

// -------- one spline eval (BYTE-IDENTICAL r3 core: lut + 3-step bisect) ---
__device__ __forceinline__ float eval1(const float x,
                                       const float* xx,            // LDS row
                                       const float* __restrict__ yyg,
                                       const float* __restrict__ ddg,
                                       const unsigned char* lrow,
                                       float& yout)
{
    const float lo = xx[0];
    const float hi = xx[NBIN - 1];
    float y, lj;
    if (x < lo) {
        const float d0 = ddg[0];
        y  = yyg[0] + (x - lo) * d0;
        lj = __logf(d0);
    } else if (x > hi) {
        const float dK = ddg[NBIN - 1];
        y  = yyg[NBIN - 1] + (x - hi) * dK;
        lj = __logf(dK);
    } else {
        int u = (int)((x + 4.0f) * (NL / 8.0f));
        u = u < 0 ? 0 : (u > NL - 1 ? NL - 1 : u);
        int klo = (int)lrow[u] - 1;
        klo = klo < 0 ? 0 : klo;
        int khi = (int)lrow[u + 1] + 2;
        khi = khi > NBIN ? NBIN : khi;
        #pragma unroll
        for (int itb = 0; itb < 3; ++itb) {
            const int mid = (klo + khi) >> 1;
            const bool le = (xx[mid] <= x);
            klo = le ? mid : klo;
            khi = le ? khi : mid;
        }
        int k = klo;
        if (k > NBIN - 2) k = NBIN - 2;

        const float xk = xx[k], xk1 = xx[k + 1];
        const float yk = yyg[k], yk1 = yyg[k + 1];
        const float dk = ddg[k], dk1 = ddg[k + 1];

        const float wdt     = xk1 - xk;
        const float inv_wdt = __fdividef(1.f, wdt);
        const float dy      = yk1 - yk;
        const float s       = dy * inv_wdt;
        const float xi      = (x - xk) * inv_wdt;
        const float om      = 1.f - xi;
        const float denom   = s + (dk1 + dk - 2.f * s) * xi * om;
        const float r       = __fdividef(1.f, denom);
        const float num     = dy * (s * xi * xi + dk * xi * om);
        y = yk + num * r;
        const float Nq = dk1 * xi * xi + 2.f * s * xi * om + dk * om * om;
        const float t2 = s * r;
        lj = __logf(t2 * t2 * Nq);
    }
    yout = y;
    return lj;
}

// ---------------- FUSED: project + spline + reconstruct -------------------
// wT is block-diagonal per patch: transforms [p*16,p*16+16) depend only on
// patch p's 16 data dims, and those dims' reconstruction depends only on
// those 16 transforms. Block = (patch, class); thread = one sample of the
// class. Eliminates the 25MB xb intermediate entirely (100MB of HBM round
// trips across pA/pB/pC) and pA/pC's un-hideable latency; the r3 spline
// core is preserved verbatim with 4x the per-thread gather ILP (16 chains).
__global__ __launch_bounds__(BLK, 4)
void p_fused(const float* __restrict__ data,   // (N, NDIM)
             const float* __restrict__ B,      // (192,16,16) [i][t]
             const float* __restrict__ kx,     // (10, NTRANS, NBIN)
             const float* __restrict__ ky,
             const float* __restrict__ kd,
             const int*   __restrict__ cls_off,
             const int*   __restrict__ inv,    // slot -> sample
             float* __restrict__ out,
             float* __restrict__ logj)         // pre-zeroed, atomic accum
{
    __shared__ float s_kx[16 * NBIN];                // 12.8 KB
    __shared__ float s_B[256];                       // 1 KB   B[p]
    __shared__ unsigned char s_lut[16 * LUTS];       // 2.18 KB (16 KB total)

    const int p   = blockIdx.x;
    const int c   = blockIdx.y;
    const int tid = threadIdx.x;

    // patch geometry (same mapping as the old pA/pC)
    const int nh  = p / 24;
    const int rem = p - nh * 24;
    const int nw  = rem / 3;
    const int ch  = rem - nw * 3;
    const int rowbase = nh * 384 + nw * 12 + ch;

    // ---- issue the per-thread sample loads EARLY (hide under staging) ----
    const int beg = cls_off[c];
    const int end = cls_off[c + 1];
    const int sl  = beg + tid;
    const bool act = (sl < end);
    int n = 0;
    float d[16];
    if (act) {
        n = inv[sl];
        const float* dr = data + (size_t)n * NDIM + rowbase;
        #pragma unroll
        for (int i = 0; i < 16; ++i)
            d[i] = dr[(i >> 2) * 96 + (i & 3) * 3];
    }

    // ---- stage knots-x + B, build LUT (r3-identical structure) ----
    const size_t kofs = ((size_t)c * NTRANS + p * 16) * NBIN;
    const float4* gx = (const float4*)(kx + kofs);
    float4* lx = (float4*)s_kx;
    #pragma unroll 1
    for (int i = tid; i < 16 * NBIN / 4; i += BLK) lx[i] = gx[i];
    if (tid < 64) ((float4*)s_B)[tid] = ((const float4*)(B + p * 256))[tid];
    __syncthreads();

    {   // LUT build: thread = (row r, chunk ch8 of 8 bin-edges)
        const int r   = tid >> 4;
        const int ch8 = tid & 15;
        const float* xx = s_kx + r * NBIN;
        const int j0 = ch8 * 8;
        const float xu0 = -4.0f + (float)j0 * (8.0f / NL);
        int klo = 0, khi = NBIN;
        #pragma unroll
        for (int it = 0; it < 8; ++it) {
            const int mid = (klo + khi) >> 1;
            const bool le = (xx[mid] <= xu0);
            klo = le ? mid : klo;
            khi = le ? khi : mid;
        }
        int k = klo;
        const int nj = (ch8 == 15) ? 9 : 8;
        unsigned char* lrow = s_lut + r * LUTS + j0;
        #pragma unroll 1
        for (int jj = 0; jj < nj; ++jj) {
            const float xuj = -4.0f + (float)(j0 + jj) * (8.0f / NL);
            while (k < NBIN - 1 && xx[k + 1] <= xuj) ++k;
            lrow[jj] = (unsigned char)k;
        }
    }
    __syncthreads();

    if (!act) return;

    // ---- projection: x[t] = sum_i B[i][t] * d[i] (B broadcast from LDS) --
    float xv[16];
    {
        float4 xq0 = make_float4(0.f, 0.f, 0.f, 0.f), xq1 = xq0, xq2 = xq0, xq3 = xq0;
        #pragma unroll
        for (int i = 0; i < 16; ++i) {
            const float di = d[i];
            const float4* Br = (const float4*)(s_B + i * 16);
            const float4 b0 = Br[0], b1 = Br[1], b2 = Br[2], b3 = Br[3];
            xq0.x += di * b0.x; xq0.y += di * b0.y; xq0.z += di * b0.z; xq0.w += di * b0.w;
            xq1.x += di * b1.x; xq1.y += di * b1.y; xq1.z += di * b1.z; xq1.w += di * b1.w;
            xq2.x += di * b2.x; xq2.y += di * b2.y; xq2.z += di * b2.z; xq2.w += di * b2.w;
            xq3.x += di * b3.x; xq3.y += di * b3.y; xq3.z += di * b3.z; xq3.w += di * b3.w;
        }
        xv[0]=xq0.x; xv[1]=xq0.y; xv[2]=xq0.z; xv[3]=xq0.w;
        xv[4]=xq1.x; xv[5]=xq1.y; xv[6]=xq1.z; xv[7]=xq1.w;
        xv[8]=xq2.x; xv[9]=xq2.y; xv[10]=xq2.z; xv[11]=xq2.w;
        xv[12]=xq3.x; xv[13]=xq3.y; xv[14]=xq3.z; xv[15]=xq3.w;
    }

    // ---- 16 independent spline evals (r3 core) -> diff[t], lj_sum --------
    const float* kyg = ky + kofs;
    const float* kdg = kd + kofs;
    float diff[16];
    float lj_sum = 0.f;
    #pragma unroll
    for (int t = 0; t < 16; ++t) {
        float y;
        lj_sum += eval1(xv[t], s_kx + t * NBIN,
                        kyg + (size_t)t * NBIN, kdg + (size_t)t * NBIN,
                        s_lut + t * LUTS, y);
        diff[t] = y - xv[t];
    }

    // ---- reconstruction: out_i = d_i + sum_t B[i][t] * diff[t] -----------
    float* op = out + (size_t)n * NDIM + rowbase;
    #pragma unroll
    for (int i = 0; i < 16; ++i) {
        const float4* Br = (const float4*)(s_B + i * 16);
        const float4 b0 = Br[0], b1 = Br[1], b2 = Br[2], b3 = Br[3];
        float acc = d[i];
        acc += b0.x * diff[0]  + b0.y * diff[1]  + b0.z * diff[2]  + b0.w * diff[3];
        acc += b1.x * diff[4]  + b1.y * diff[5]  + b1.z * diff[6]  + b1.w * diff[7];
        acc += b2.x * diff[8]  + b2.y * diff[9]  + b2.z * diff[10] + b2.w * diff[11];
        acc += b3.x * diff[12] + b3.y * diff[13] + b3.z * diff[14] + b3.w * diff[15];
        op[(i >> 2) * 96 + (i & 3) * 3] = acc;
    }

    atomicAdd(&logj[n], lj_sum);
}

extern "C" void kernel_launch(void* const* d_in, const int* in_sizes, int n_in,
                              void* d_out, int out_size, void* d_ws, size_t ws_size,
                              hipStream_t stream) {
    const float* data  = (const float*)d_in[0];
    const int*   label = (const int*)  d_in[1];
    const float* B     = (const float*)d_in[2];
    const float* kx    = (const float*)d_in[3];
    const float* ky    = (const float*)d_in[4];
    const float* kd    = (const float*)d_in[5];

    float* out  = (float*)d_out;
    float* logj = (float*)d_out + (size_t)NSAMP * NDIM;

    // ws layout (xb intermediate eliminated)
    char* ws = (char*)d_ws;
    size_t off = 0;
    int* inv     = (int*)(ws + off); off += NSAMP * 4;
    int* cls_off = (int*)(ws + off); off += 64;

    p0_prep<<<1, 1024, 0, stream>>>(label, inv, cls_off, logj);
    dim3 gridF(NPATCH, NCLASS);
    p_fused<<<gridF, BLK, 0, stream>>>(data, B, kx, ky, kd, cls_off, inv, out, logj);
}

// Round 11
// 207.037 us; speedup vs baseline: 2.1286x; 2.1286x over previous
//
#include <hip/hip_runtime.h>

// Problem constants (from reference)
constexpr int NSAMP  = 2048;
constexpr int NDIM   = 3072;   // H*W*C = 32*32*3
constexpr int NTRANS = 3072;   // NKERNEL*NCOMP = 192*16
constexpr int NBIN   = 200;
constexpr int NCLASS = 10;
constexpr int NPATCH = 192;
constexpr int BLK    = 256;
constexpr int DSTR   = 20;          // s_diff row stride: 16B-aligned
constexpr int SA     = 4;           // samples per pA block
constexpr int HD     = 1536;        // pA: dims per z-half
constexpr int HP     = 96;          // pA: patches per z-half
constexpr int SC     = 4;           // samples per pC group
constexpr int QP     = 48;          // pC: patches per quarter
constexpr int QD     = 768;         // pC: output dims per quarter
constexpr int NL     = 128;         // pB search-LUT bins over [-4,4]; bracket<=8
constexpr int LUTS   = 136;         // LDS lut row stride in bytes

// xb layout: one 64B line per (p, sl) — r3-proven. The xb intermediate is
// load-bearing (r10: fusing it away -> 1GB of line-granularity scatter).
__device__ __forceinline__ float4* xb_line(float* xb, int p, int sl) {
    return (float4*)(xb + ((size_t)p * NSAMP + (sl ^ (p & 63))) * 16);
}
__device__ __forceinline__ const float4* xb_line_c(const float* xb, int p, int sl) {
    return (const float4*)(xb + ((size_t)p * NSAMP + (sl ^ (p & 63))) * 16);
}

// ---------------- P0: class bucketing (ballot) + logj_slot zeroing --------
__global__ __launch_bounds__(1024)
void p0_prep(const int* __restrict__ label,
             int* __restrict__ slot,      // (NSAMP)
             int* __restrict__ cls_off,   // (NCLASS+1)
             float* __restrict__ logj_slot)
{
    __shared__ int s_lab[NSAMP];
    __shared__ int s_cnt[32][NCLASS];
    __shared__ int s_pre[32][NCLASS];
    __shared__ int s_tot[NCLASS];
    __shared__ int s_off[NCLASS + 1];
    const int tid  = threadIdx.x;
    const int lane = tid & 63;
    const int wv   = tid >> 6;

    for (int i = tid; i < NSAMP; i += 1024) {
        s_lab[i] = label[i];
        logj_slot[i] = 0.f;              // pB accumulates via atomicAdd
    }
    __syncthreads();

    const unsigned long long ltmask = ((unsigned long long)1 << lane) - 1;
    int myrank[2], myc[2];
    #pragma unroll
    for (int pass = 0; pass < 2; ++pass) {
        const int n = pass * 1024 + tid;
        const int c = s_lab[n];
        myc[pass] = c;
        int r = 0;
        #pragma unroll
        for (int cls = 0; cls < NCLASS; ++cls) {
            const unsigned long long b = __ballot(c == cls);
            if (lane == 0) s_cnt[pass * 16 + wv][cls] = __popcll(b);
            if (cls == c)  r = __popcll(b & ltmask);
        }
        myrank[pass] = r;
    }
    __syncthreads();

    if (tid < 32 * NCLASS) {
        const int seg = tid & 31;
        const int cls = tid >> 5;
        int acc = 0;
        for (int s = 0; s < seg; ++s) acc += s_cnt[s][cls];
        s_pre[seg][cls] = acc;
        if (seg == 31) s_tot[cls] = acc + s_cnt[31][cls];
    }
    __syncthreads();
    if (tid == 0) {
        int a = 0;
        for (int c = 0; c < NCLASS; ++c) { s_off[c] = a; a += s_tot[c]; }
        s_off[NCLASS] = a;
    }
    __syncthreads();

    #pragma unroll
    for (int pass = 0; pass < 2; ++pass) {
        const int n   = pass * 1024 + tid;
        const int seg = pass * 16 + wv;
        const int c   = myc[pass];
        slot[n] = s_off[c] + s_pre[seg][c] + myrank[pass];
    }
    if (tid <= NCLASS) cls_off[tid] = s_off[tid];
}

// ---------------- A: x = data @ wT, SA=4, z-halved dims -------------------
// Block (b, z): stages only dims [z*1536, +1536) of its 4 samples (24 KB)
// and computes patches [z*96, +96). IDENTICAL traffic and B-reuse to the r3
// pA (each data dim staged once, each (p,q4) B-column read once), but grid
// 512 -> 1024 = 4 blocks/CU (was 2, 25% occupancy).
__global__ __launch_bounds__(BLK, 4)
void pA_project(const float* __restrict__ data,  // (N, NDIM)
                const float* __restrict__ B,     // (192,16,16) row-major [i][c]
                const int*   __restrict__ slot,
                float* __restrict__ xb)
{
    __shared__ float s_data[SA][HD];             // 24 KB
    const int b   = blockIdx.x;
    const int z   = blockIdx.y;
    const int tid = threadIdx.x;
    const int n0  = b * SA;
    const int dof = z * HD;

    #pragma unroll
    for (int s = 0; s < SA; ++s) {
        const float4* dr = (const float4*)(data + (size_t)(n0 + s) * NDIM + dof);
        float4* sd = (float4*)s_data[s];
        sd[tid] = dr[tid];
        if (tid < HD / 4 - BLK) sd[tid + BLK] = dr[tid + BLK];   // 384 f4/sample
    }
    int sls[SA];
    #pragma unroll
    for (int s = 0; s < SA; ++s) sls[s] = slot[n0 + s];
    __syncthreads();

    #pragma unroll 1
    for (int e = tid; e < HP * 4; e += BLK) {   // 384 tasks: e = (p-z*96)*4+q4
        const int p   = z * HP + (e >> 2);
        const int q4  = e & 3;
        const int nh  = p / 24;
        const int rem = p - nh * 24;
        const int nw  = rem / 3;
        const int ch  = rem - nw * 3;
        const int rowbase = nh * 384 + nw * 12 + ch - dof;   // local to half

        float4 Bp[16];                       // Bp[i] = B[p][i][q4*4..+3]
        const float4* Bg = (const float4*)(B + p * 256 + q4 * 4);
        #pragma unroll
        for (int i = 0; i < 16; ++i) Bp[i] = Bg[i * 4];

        #pragma unroll
        for (int s = 0; s < SA; ++s) {
            float dv[16];
            #pragma unroll
            for (int i = 0; i < 16; ++i)
                dv[i] = s_data[s][rowbase + (i >> 2) * 96 + (i & 3) * 3];

            float acc[4] = {0.f, 0.f, 0.f, 0.f};
            #pragma unroll
            for (int i = 0; i < 16; ++i) {
                acc[0] += Bp[i].x * dv[i];
                acc[1] += Bp[i].y * dv[i];
                acc[2] += Bp[i].z * dv[i];
                acc[3] += Bp[i].w * dv[i];
            }
            *(xb_line(xb, p, sls[s]) + q4) =
                make_float4(acc[0], acc[1], acc[2], acc[3]);
        }
    }
}

// ---------------- B: spline — r3 core, z-split sample range ---------------
// Grid (192, 10, 2): z halves the class's slot range. Staging, LUT build,
// and the inner loop are BYTE-IDENTICAL to the proven r3 kernel (r4-r7
// reworks all regressed — do not perturb the core). Occupancy 60% -> ~90%
// (3840 blocks = 15/CU vs 7.5), tail halved; kx re-staged once more
// (+24.6MB FETCH, ~3us of BW, hidden under the gather streams).
__global__ __launch_bounds__(BLK, 8)
void pB_spline(const float* __restrict__ kx,   // (10, NTRANS, NBIN)
               const float* __restrict__ ky,
               const float* __restrict__ kd,
               const int*   __restrict__ cls_off,
               float* __restrict__ xb,          // in: x, out: diff (in place)
               float* __restrict__ logj_slot)   // (NSAMP), pre-zeroed
{
    __shared__ float s_kx[16 * NBIN];                // 12.8 KB
    __shared__ unsigned char s_lut[16 * LUTS];       // 2.18 KB (15.0 KB total)

    const int p   = blockIdx.x;
    const int c   = blockIdx.y;
    const int zz  = blockIdx.z;
    const int tid = threadIdx.x;
    const int t0  = p * 16;

    const size_t kofs = ((size_t)c * NTRANS + t0) * NBIN;
    const float4* gx = (const float4*)(kx + kofs);
    float4* lx = (float4*)s_kx;
    #pragma unroll 1
    for (int i = tid; i < 16 * NBIN / 4; i += BLK) lx[i] = gx[i];
    __syncthreads();

    // LUT build: thread = (row r, chunk ch of 8 bin-edges). Bisect once for
    // the chunk's first edge, then walk k forward.
    {
        const int r  = tid >> 4;
        const int ch = tid & 15;
        const float* xx = s_kx + r * NBIN;
        const int j0 = ch * 8;
        const float xu0 = -4.0f + (float)j0 * (8.0f / NL);
        int klo = 0, khi = NBIN;
        #pragma unroll
        for (int it = 0; it < 8; ++it) {
            const int mid = (klo + khi) >> 1;
            const bool le = (xx[mid] <= xu0);
            klo = le ? mid : klo;
            khi = le ? khi : mid;
        }
        int k = klo;
        const int nj = (ch == 15) ? 9 : 8;       // chunk 15 also covers u=128
        unsigned char* lrow = s_lut + r * LUTS + j0;
        #pragma unroll 1
        for (int jj = 0; jj < nj; ++jj) {
            const float xuj = -4.0f + (float)(j0 + jj) * (8.0f / NL);
            while (k < NBIN - 1 && xx[k + 1] <= xuj) ++k;
            lrow[jj] = (unsigned char)k;
        }
    }
    __syncthreads();

    const int qq  = tid & 3;
    const int sid = tid >> 2;
    const float* sxx = s_kx + qq * 4 * NBIN;
    const float* kyp = ky + kofs + (size_t)(qq * 4) * NBIN;
    const float* kdp = kd + kofs + (size_t)(qq * 4) * NBIN;

    // z-split of the class's slot range (disjoint halves: no new races)
    const int beg0 = cls_off[c];
    const int end0 = cls_off[c + 1];
    const int h0   = (end0 - beg0 + 1) >> 1;
    const int beg  = beg0 + zz * h0;
    const int end  = zz ? end0 : beg0 + h0;
    const int nit  = (end - beg + 63) >> 6;

    // prologue: load iteration 0's line
    int sl = beg + sid;
    float4 v = make_float4(0.f, 0.f, 0.f, 0.f);
    float4* lcur = nullptr;
    if (sl < end) { lcur = xb_line(xb, p, sl) + qq; v = *lcur; }

    #pragma unroll 1
    for (int it = 0; it < nit; ++it) {
        // prefetch next iteration's line before the heavy math
        const int sln = sl + 64;
        float4 vn = make_float4(0.f, 0.f, 0.f, 0.f);
        float4* lnx = nullptr;
        if (it + 1 < nit && sln < end) { lnx = xb_line(xb, p, sln) + qq; vn = *lnx; }

        if (lcur) {
            float xs[4] = {v.x, v.y, v.z, v.w};
            float lj_sum = 0.f;
            #pragma unroll
            for (int j = 0; j < 4; ++j) {
                const float* xx  = sxx + j * NBIN;
                const float* yyg = kyp + j * NBIN;
                const float* ddg = kdp + j * NBIN;
                const unsigned char* lrow = s_lut + (qq * 4 + j) * LUTS;
                const float x  = xs[j];
                const float lo = xx[0];
                const float hi = xx[NBIN - 1];

                float y, lj;
                if (x < lo) {
                    const float d0 = ddg[0];
                    y  = yyg[0] + (x - lo) * d0;
                    lj = __logf(d0);
                } else if (x > hi) {
                    const float dK = ddg[NBIN - 1];
                    y  = yyg[NBIN - 1] + (x - hi) * dK;
                    lj = __logf(dK);
                } else {
                    int u = (int)((x + 4.0f) * (NL / 8.0f));
                    u = u < 0 ? 0 : (u > NL - 1 ? NL - 1 : u);
                    int klo = (int)lrow[u] - 1;
                    klo = klo < 0 ? 0 : klo;
                    int khi = (int)lrow[u + 1] + 2;
                    khi = khi > NBIN ? NBIN : khi;
                    #pragma unroll
                    for (int itb = 0; itb < 3; ++itb) {
                        const int mid = (klo + khi) >> 1;
                        const bool le = (xx[mid] <= x);
                        klo = le ? mid : klo;
                        khi = le ? khi : mid;
                    }
                    int k = klo;
                    if (k > NBIN - 2) k = NBIN - 2;

                    const float xk = xx[k], xk1 = xx[k + 1];
                    const float yk = yyg[k], yk1 = yyg[k + 1];
                    const float dk = ddg[k], dk1 = ddg[k + 1];

                    const float wdt     = xk1 - xk;
                    const float inv_wdt = __fdividef(1.f, wdt);
                    const float dy      = yk1 - yk;
                    const float s       = dy * inv_wdt;
                    const float xi      = (x - xk) * inv_wdt;
                    const float om      = 1.f - xi;
                    const float denom   = s + (dk1 + dk - 2.f * s) * xi * om;
                    const float r       = __fdividef(1.f, denom);
                    const float num     = dy * (s * xi * xi + dk * xi * om);
                    y = yk + num * r;
                    const float Nq = dk1 * xi * xi + 2.f * s * xi * om + dk * om * om;
                    const float t2 = s * r;
                    lj = __logf(t2 * t2 * Nq);
                }
                xs[j] = y - x;
                lj_sum += lj;
            }

            *lcur = make_float4(xs[0], xs[1], xs[2], xs[3]);

            lj_sum += __shfl_xor(lj_sum, 1);
            lj_sum += __shfl_xor(lj_sum, 2);
            if (qq == 0) atomicAdd(&logj_slot[sl], lj_sum);
        }

        sl = sln; lcur = lnx; v = vn;
    }
}

// ---------------- C: out = data + diff @ wT^T, quarter-dim split ----------
// (r9 version: neutral vs r3 but keeps full reuse at 8 blocks/CU.)
__global__ __launch_bounds__(BLK, 8)
void pC_recon(const float* __restrict__ data,
              const float* __restrict__ B,
              const int*   __restrict__ slot,
              const float* __restrict__ xb,        // diff, blocked layout
              const float* __restrict__ logj_slot,
              float* __restrict__ out,
              float* __restrict__ logj)
{
    __shared__ float s_diff[SC][QP * DSTR];       // 15.36 KB
    const int g   = blockIdx.x;                   // sample group
    const int qtr = blockIdx.y;                   // dim quarter
    const int tid = threadIdx.x;
    const int n0  = g * SC;
    const int pq  = qtr * QP;                     // first patch of quarter

    int sls[SC];
    #pragma unroll
    for (int s = 0; s < SC; ++s) sls[s] = slot[n0 + s];

    // stage SC*QP lines (= 768 float4) -> 3 per thread
    #pragma unroll
    for (int jj = 0; jj < 3; ++jj) {
        const int e  = tid + BLK * jj;      // 0..767
        const int s  = e / (QP * 4);
        const int r  = e - s * (QP * 4);
        const int pl = r >> 2;
        const int q  = r & 3;
        const float4 v = *(xb_line_c(xb, pq + pl, sls[s]) + q);
        *(float4*)&s_diff[s][pl * DSTR + q * 4] = v;
    }
    if (qtr == 0 && tid < SC) logj[n0 + tid] = logj_slot[sls[tid]];
    __syncthreads();

    #pragma unroll 1
    for (int j = 0; j < QD / BLK; ++j) {          // 3 iterations
        const int d  = qtr * QD + tid + BLK * j;
        const int ch = d % 3;
        const int hw = d / 3;
        const int w  = hw & 31;
        const int h  = hw >> 5;
        const int p  = ((h >> 2) * 8 + (w >> 2)) * 3 + ch;   // in [pq, pq+QP)
        const int pl = p - pq;
        const int i  = (h & 3) * 4 + (w & 3);

        const float4* Bp4 = (const float4*)(B + p * 256 + i * 16);
        const float4 b0 = Bp4[0], b1 = Bp4[1], b2 = Bp4[2], b3 = Bp4[3];

        #pragma unroll
        for (int s = 0; s < SC; ++s) {
            const float4* dp4 = (const float4*)&s_diff[s][pl * DSTR];
            const float4 d0 = dp4[0], d1 = dp4[1], d2 = dp4[2], d3 = dp4[3];
            float acc = data[(size_t)(n0 + s) * NDIM + d];
            acc += b0.x * d0.x + b0.y * d0.y + b0.z * d0.z + b0.w * d0.w;
            acc += b1.x * d1.x + b1.y * d1.y + b1.z * d1.z + b1.w * d1.w;
            acc += b2.x * d2.x + b2.y * d2.y + b2.z * d2.z + b2.w * d2.w;
            acc += b3.x * d3.x + b3.y * d3.y + b3.z * d3.z + b3.w * d3.w;
            out[(size_t)(n0 + s) * NDIM + d] = acc;
        }
    }
}

extern "C" void kernel_launch(void* const* d_in, const int* in_sizes, int n_in,
                              void* d_out, int out_size, void* d_ws, size_t ws_size,
                              hipStream_t stream) {
    const float* data  = (const float*)d_in[0];
    const int*   label = (const int*)  d_in[1];
    const float* B     = (const float*)d_in[2];
    const float* kx    = (const float*)d_in[3];
    const float* ky    = (const float*)d_in[4];
    const float* kd    = (const float*)d_in[5];

    float* out  = (float*)d_out;
    float* logj = (float*)d_out + (size_t)NSAMP * NDIM;

    // ws layout
    char* ws = (char*)d_ws;
    size_t off = 0;
    float* xb        = (float*)(ws + off); off += (size_t)NPATCH * NSAMP * 16 * 4; // 25.2 MB
    float* logj_slot = (float*)(ws + off); off += NSAMP * 4;
    int*   slot      = (int*)  (ws + off); off += NSAMP * 4;
    int*   cls_off   = (int*)  (ws + off); off += 64;

    p0_prep   <<<1, 1024, 0, stream>>>(label, slot, cls_off, logj_slot);
    dim3 gridA(NSAMP / SA, 2);
    pA_project<<<gridA, BLK, 0, stream>>>(data, B, slot, xb);
    dim3 gridB(NPATCH, NCLASS, 2);
    pB_spline <<<gridB, BLK, 0, stream>>>(kx, ky, kd, cls_off, xb, logj_slot);
    dim3 gridC(NSAMP / SC, NDIM / QD);
    pC_recon  <<<gridC, BLK, 0, stream>>>(data, B, slot, xb, logj_slot, out, logj);
}

// Round 12
// 196.718 us; speedup vs baseline: 2.2403x; 1.0525x over previous
//
#include <hip/hip_runtime.h>

// Problem constants (from reference)
constexpr int NSAMP  = 2048;
constexpr int NDIM   = 3072;   // H*W*C = 32*32*3
constexpr int NTRANS = 3072;   // NKERNEL*NCOMP = 192*16
constexpr int NBIN   = 200;
constexpr int NCLASS = 10;
constexpr int NPATCH = 192;
constexpr int BLK    = 256;
constexpr int DSTR   = 20;          // s_diff row stride: 16B-aligned
constexpr int SA     = 4;           // samples per pA block
constexpr int SC     = 4;           // samples per pC group
constexpr int QP     = 48;          // pC: patches per quarter
constexpr int QD     = 768;         // pC: output dims per quarter
constexpr int NL     = 128;         // pB search-LUT bins over [-4,4]; bracket<=8
constexpr int LUTS   = 136;         // LDS lut row stride in bytes

// xb layout: one 64B line per (p, sl) — r3-proven. The xb intermediate is
// load-bearing (r10: fusing it away -> 1GB of line-granularity scatter).
__device__ __forceinline__ float4* xb_line(float* xb, int p, int sl) {
    return (float4*)(xb + ((size_t)p * NSAMP + (sl ^ (p & 63))) * 16);
}
__device__ __forceinline__ const float4* xb_line_c(const float* xb, int p, int sl) {
    return (const float4*)(xb + ((size_t)p * NSAMP + (sl ^ (p & 63))) * 16);
}

// ---------------- P0: class bucketing (ballot) + logj_slot zeroing --------
__global__ __launch_bounds__(1024)
void p0_prep(const int* __restrict__ label,
             int* __restrict__ slot,      // (NSAMP)
             int* __restrict__ cls_off,   // (NCLASS+1)
             float* __restrict__ logj_slot)
{
    __shared__ int s_lab[NSAMP];
    __shared__ int s_cnt[32][NCLASS];
    __shared__ int s_pre[32][NCLASS];
    __shared__ int s_tot[NCLASS];
    __shared__ int s_off[NCLASS + 1];
    const int tid  = threadIdx.x;
    const int lane = tid & 63;
    const int wv   = tid >> 6;

    for (int i = tid; i < NSAMP; i += 1024) {
        s_lab[i] = label[i];
        logj_slot[i] = 0.f;              // pB accumulates via atomicAdd
    }
    __syncthreads();

    const unsigned long long ltmask = ((unsigned long long)1 << lane) - 1;
    int myrank[2], myc[2];
    #pragma unroll
    for (int pass = 0; pass < 2; ++pass) {
        const int n = pass * 1024 + tid;
        const int c = s_lab[n];
        myc[pass] = c;
        int r = 0;
        #pragma unroll
        for (int cls = 0; cls < NCLASS; ++cls) {
            const unsigned long long b = __ballot(c == cls);
            if (lane == 0) s_cnt[pass * 16 + wv][cls] = __popcll(b);
            if (cls == c)  r = __popcll(b & ltmask);
        }
        myrank[pass] = r;
    }
    __syncthreads();

    if (tid < 32 * NCLASS) {
        const int seg = tid & 31;
        const int cls = tid >> 5;
        int acc = 0;
        for (int s = 0; s < seg; ++s) acc += s_cnt[s][cls];
        s_pre[seg][cls] = acc;
        if (seg == 31) s_tot[cls] = acc + s_cnt[31][cls];
    }
    __syncthreads();
    if (tid == 0) {
        int a = 0;
        for (int c = 0; c < NCLASS; ++c) { s_off[c] = a; a += s_tot[c]; }
        s_off[NCLASS] = a;
    }
    __syncthreads();

    #pragma unroll
    for (int pass = 0; pass < 2; ++pass) {
        const int n   = pass * 1024 + tid;
        const int seg = pass * 16 + wv;
        const int c   = myc[pass];
        slot[n] = s_off[c] + s_pre[seg][c] + myrank[pass];
    }
    if (tid <= NCLASS) cls_off[tid] = s_off[tid];
}

// ---------------- A: x = data @ wT, SA=4 samples/block (r9 exact) ---------
__global__ __launch_bounds__(BLK, 4)
void pA_project(const float* __restrict__ data,  // (N, NDIM)
                const float* __restrict__ B,     // (192,16,16) row-major [i][c]
                const int*   __restrict__ slot,
                float* __restrict__ xb)
{
    __shared__ float s_data[SA][NDIM];           // 48 KB
    const int b   = blockIdx.x;
    const int tid = threadIdx.x;
    const int n0  = b * SA;

    #pragma unroll
    for (int s = 0; s < SA; ++s) {
        const float4* dr = (const float4*)(data + (size_t)(n0 + s) * NDIM);
        float4* sd = (float4*)s_data[s];
        #pragma unroll
        for (int j = 0; j < 3; ++j)
            sd[tid + BLK * j] = dr[tid + BLK * j];
    }
    int sls[SA];
    #pragma unroll
    for (int s = 0; s < SA; ++s) sls[s] = slot[n0 + s];
    __syncthreads();

    #pragma unroll 1
    for (int jj = 0; jj < 3; ++jj) {
        const int tau = tid + BLK * jj;     // 0..767 = p*4 + q4
        const int p   = tau >> 2;
        const int q4  = tau & 3;
        const int nh  = p / 24;
        const int rem = p - nh * 24;
        const int nw  = rem / 3;
        const int ch  = rem - nw * 3;
        const int rowbase = nh * 384 + nw * 12 + ch;

        float4 Bp[16];                       // Bp[i] = B[p][i][q4*4..+3]
        const float4* Bg = (const float4*)(B + p * 256 + q4 * 4);
        #pragma unroll
        for (int i = 0; i < 16; ++i) Bp[i] = Bg[i * 4];

        #pragma unroll
        for (int s = 0; s < SA; ++s) {
            float dv[16];
            #pragma unroll
            for (int i = 0; i < 16; ++i)
                dv[i] = s_data[s][rowbase + (i >> 2) * 96 + (i & 3) * 3];

            float acc[4] = {0.f, 0.f, 0.f, 0.f};
            #pragma unroll
            for (int i = 0; i < 16; ++i) {
                acc[0] += Bp[i].x * dv[i];
                acc[1] += Bp[i].y * dv[i];
                acc[2] += Bp[i].z * dv[i];
                acc[3] += Bp[i].w * dv[i];
            }
            *(xb_line(xb, p, sls[s]) + q4) =
                make_float4(acc[0], acc[1], acc[2], acc[3]);
        }
    }
}

// ---------------- B: spline — BYTE-FOR-BYTE r3 (proven 55us) --------------
// r4 (layout), r5 (staging), r6 (half-block staging), r7 (ILP x2), r11
// (z-split occupancy): SIX falsified mutations. Do not perturb.
__global__ __launch_bounds__(BLK, 8)
void pB_spline(const float* __restrict__ kx,   // (10, NTRANS, NBIN)
               const float* __restrict__ ky,
               const float* __restrict__ kd,
               const int*   __restrict__ cls_off,
               float* __restrict__ xb,          // in: x, out: diff (in place)
               float* __restrict__ logj_slot)   // (NSAMP), pre-zeroed
{
    __shared__ float s_kx[16 * NBIN];                // 12.8 KB
    __shared__ unsigned char s_lut[16 * LUTS];       // 2.18 KB (15.0 KB total)

    const int p   = blockIdx.x;
    const int c   = blockIdx.y;
    const int tid = threadIdx.x;
    const int t0  = p * 16;

    const size_t kofs = ((size_t)c * NTRANS + t0) * NBIN;
    const float4* gx = (const float4*)(kx + kofs);
    float4* lx = (float4*)s_kx;
    #pragma unroll 1
    for (int i = tid; i < 16 * NBIN / 4; i += BLK) lx[i] = gx[i];
    __syncthreads();

    // LUT build: thread = (row r, chunk ch of 8 bin-edges). Bisect once for
    // the chunk's first edge, then walk k forward.
    {
        const int r  = tid >> 4;
        const int ch = tid & 15;
        const float* xx = s_kx + r * NBIN;
        const int j0 = ch * 8;
        const float xu0 = -4.0f + (float)j0 * (8.0f / NL);
        int klo = 0, khi = NBIN;
        #pragma unroll
        for (int it = 0; it < 8; ++it) {
            const int mid = (klo + khi) >> 1;
            const bool le = (xx[mid] <= xu0);
            klo = le ? mid : klo;
            khi = le ? khi : mid;
        }
        int k = klo;
        const int nj = (ch == 15) ? 9 : 8;       // chunk 15 also covers u=128
        unsigned char* lrow = s_lut + r * LUTS + j0;
        #pragma unroll 1
        for (int jj = 0; jj < nj; ++jj) {
            const float xuj = -4.0f + (float)(j0 + jj) * (8.0f / NL);
            while (k < NBIN - 1 && xx[k + 1] <= xuj) ++k;
            lrow[jj] = (unsigned char)k;
        }
    }
    __syncthreads();

    const int qq  = tid & 3;
    const int sid = tid >> 2;
    const float* sxx = s_kx + qq * 4 * NBIN;
    const float* kyp = ky + kofs + (size_t)(qq * 4) * NBIN;
    const float* kdp = kd + kofs + (size_t)(qq * 4) * NBIN;

    const int beg = cls_off[c];
    const int end = cls_off[c + 1];
    const int nit = (end - beg + 63) >> 6;

    // prologue: load iteration 0's line
    int sl = beg + sid;
    float4 v = make_float4(0.f, 0.f, 0.f, 0.f);
    float4* lcur = nullptr;
    if (sl < end) { lcur = xb_line(xb, p, sl) + qq; v = *lcur; }

    #pragma unroll 1
    for (int it = 0; it < nit; ++it) {
        // prefetch next iteration's line before the heavy math
        const int sln = sl + 64;
        float4 vn = make_float4(0.f, 0.f, 0.f, 0.f);
        float4* lnx = nullptr;
        if (it + 1 < nit && sln < end) { lnx = xb_line(xb, p, sln) + qq; vn = *lnx; }

        if (lcur) {
            float xs[4] = {v.x, v.y, v.z, v.w};
            float lj_sum = 0.f;
            #pragma unroll
            for (int j = 0; j < 4; ++j) {
                const float* xx  = sxx + j * NBIN;
                const float* yyg = kyp + j * NBIN;
                const float* ddg = kdp + j * NBIN;
                const unsigned char* lrow = s_lut + (qq * 4 + j) * LUTS;
                const float x  = xs[j];
                const float lo = xx[0];
                const float hi = xx[NBIN - 1];

                float y, lj;
                if (x < lo) {
                    const float d0 = ddg[0];
                    y  = yyg[0] + (x - lo) * d0;
                    lj = __logf(d0);
                } else if (x > hi) {
                    const float dK = ddg[NBIN - 1];
                    y  = yyg[NBIN - 1] + (x - hi) * dK;
                    lj = __logf(dK);
                } else {
                    int u = (int)((x + 4.0f) * (NL / 8.0f));
                    u = u < 0 ? 0 : (u > NL - 1 ? NL - 1 : u);
                    int klo = (int)lrow[u] - 1;
                    klo = klo < 0 ? 0 : klo;
                    int khi = (int)lrow[u + 1] + 2;
                    khi = khi > NBIN ? NBIN : khi;
                    #pragma unroll
                    for (int itb = 0; itb < 3; ++itb) {
                        const int mid = (klo + khi) >> 1;
                        const bool le = (xx[mid] <= x);
                        klo = le ? mid : klo;
                        khi = le ? khi : mid;
                    }
                    int k = klo;
                    if (k > NBIN - 2) k = NBIN - 2;

                    const float xk = xx[k], xk1 = xx[k + 1];
                    const float yk = yyg[k], yk1 = yyg[k + 1];
                    const float dk = ddg[k], dk1 = ddg[k + 1];

                    const float wdt     = xk1 - xk;
                    const float inv_wdt = __fdividef(1.f, wdt);
                    const float dy      = yk1 - yk;
                    const float s       = dy * inv_wdt;
                    const float xi      = (x - xk) * inv_wdt;
                    const float om      = 1.f - xi;
                    const float denom   = s + (dk1 + dk - 2.f * s) * xi * om;
                    const float r       = __fdividef(1.f, denom);
                    const float num     = dy * (s * xi * xi + dk * xi * om);
                    y = yk + num * r;
                    const float Nq = dk1 * xi * xi + 2.f * s * xi * om + dk * om * om;
                    const float t2 = s * r;
                    lj = __logf(t2 * t2 * Nq);
                }
                xs[j] = y - x;
                lj_sum += lj;
            }

            *lcur = make_float4(xs[0], xs[1], xs[2], xs[3]);

            lj_sum += __shfl_xor(lj_sum, 1);
            lj_sum += __shfl_xor(lj_sum, 2);
            if (qq == 0) atomicAdd(&logj_slot[sl], lj_sum);
        }

        sl = sln; lcur = lnx; v = vn;
    }
}

// ---------------- C: out = data + diff @ wT^T, quarter-dim split ----------
// r9 structure + ONE change: all 12 B float4 loads (compile-time addresses,
// independent of LDS) are issued BEFORE the staging barrier -> one L2
// latency exposure instead of 3 serial ones, overlapped with the scattered
// xb staging. VGPR ~90 -> launch_bounds(256,4); r9 proved pC is occupancy-
// insensitive (2 vs 8 blocks/CU neutral), so 4 blocks/CU is safe.
__global__ __launch_bounds__(BLK, 4)
void pC_recon(const float* __restrict__ data,
              const float* __restrict__ B,
              const int*   __restrict__ slot,
              const float* __restrict__ xb,        // diff, blocked layout
              const float* __restrict__ logj_slot,
              float* __restrict__ out,
              float* __restrict__ logj)
{
    __shared__ float s_diff[SC][QP * DSTR];       // 15.36 KB
    const int g   = blockIdx.x;                   // sample group
    const int qtr = blockIdx.y;                   // dim quarter
    const int tid = threadIdx.x;
    const int n0  = g * SC;
    const int pq  = qtr * QP;                     // first patch of quarter

    int sls[SC];
    #pragma unroll
    for (int s = 0; s < SC; ++s) sls[s] = slot[n0 + s];

    // precompute geometry + issue ALL B row loads up front
    int pl_j[3], d_j[3];
    float4 Bv[3][4];
    #pragma unroll
    for (int j = 0; j < 3; ++j) {
        const int d  = qtr * QD + tid + BLK * j;
        const int ch = d % 3;
        const int hw = d / 3;
        const int w  = hw & 31;
        const int h  = hw >> 5;
        const int p  = ((h >> 2) * 8 + (w >> 2)) * 3 + ch;   // in [pq, pq+QP)
        pl_j[j] = p - pq;
        d_j[j]  = d;
        const int i = (h & 3) * 4 + (w & 3);
        const float4* Bp4 = (const float4*)(B + p * 256 + i * 16);
        Bv[j][0] = Bp4[0]; Bv[j][1] = Bp4[1];
        Bv[j][2] = Bp4[2]; Bv[j][3] = Bp4[3];
    }

    // stage SC*QP lines (= 768 float4) -> 3 per thread
    #pragma unroll
    for (int jj = 0; jj < 3; ++jj) {
        const int e  = tid + BLK * jj;      // 0..767
        const int s  = e / (QP * 4);
        const int r  = e - s * (QP * 4);
        const int pl = r >> 2;
        const int q  = r & 3;
        const float4 v = *(xb_line_c(xb, pq + pl, sls[s]) + q);
        *(float4*)&s_diff[s][pl * DSTR + q * 4] = v;
    }
    if (qtr == 0 && tid < SC) logj[n0 + tid] = logj_slot[sls[tid]];
    __syncthreads();

    #pragma unroll
    for (int j = 0; j < 3; ++j) {
        const int d  = d_j[j];
        const int pl = pl_j[j];
        const float4 b0 = Bv[j][0], b1 = Bv[j][1], b2 = Bv[j][2], b3 = Bv[j][3];

        #pragma unroll
        for (int s = 0; s < SC; ++s) {
            const float4* dp4 = (const float4*)&s_diff[s][pl * DSTR];
            const float4 d0 = dp4[0], d1 = dp4[1], d2 = dp4[2], d3 = dp4[3];
            float acc = data[(size_t)(n0 + s) * NDIM + d];
            acc += b0.x * d0.x + b0.y * d0.y + b0.z * d0.z + b0.w * d0.w;
            acc += b1.x * d1.x + b1.y * d1.y + b1.z * d1.z + b1.w * d1.w;
            acc += b2.x * d2.x + b2.y * d2.y + b2.z * d2.z + b2.w * d2.w;
            acc += b3.x * d3.x + b3.y * d3.y + b3.z * d3.z + b3.w * d3.w;
            out[(size_t)(n0 + s) * NDIM + d] = acc;
        }
    }
}

extern "C" void kernel_launch(void* const* d_in, const int* in_sizes, int n_in,
                              void* d_out, int out_size, void* d_ws, size_t ws_size,
                              hipStream_t stream) {
    const float* data  = (const float*)d_in[0];
    const int*   label = (const int*)  d_in[1];
    const float* B     = (const float*)d_in[2];
    const float* kx    = (const float*)d_in[3];
    const float* ky    = (const float*)d_in[4];
    const float* kd    = (const float*)d_in[5];

    float* out  = (float*)d_out;
    float* logj = (float*)d_out + (size_t)NSAMP * NDIM;

    // ws layout
    char* ws = (char*)d_ws;
    size_t off = 0;
    float* xb        = (float*)(ws + off); off += (size_t)NPATCH * NSAMP * 16 * 4; // 25.2 MB
    float* logj_slot = (float*)(ws + off); off += NSAMP * 4;
    int*   slot      = (int*)  (ws + off); off += NSAMP * 4;
    int*   cls_off   = (int*)  (ws + off); off += 64;

    p0_prep   <<<1, 1024, 0, stream>>>(label, slot, cls_off, logj_slot);
    pA_project<<<NSAMP / SA, BLK, 0, stream>>>(data, B, slot, xb);
    dim3 gridB(NPATCH, NCLASS);
    pB_spline <<<gridB, BLK, 0, stream>>>(kx, ky, kd, cls_off, xb, logj_slot);
    dim3 gridC(NSAMP / SC, NDIM / QD);
    pC_recon  <<<gridC, BLK, 0, stream>>>(data, B, slot, xb, logj_slot, out, logj);
}